// Round 9
// baseline (373.514 us; speedup 1.0000x reference)
//
#include <hip/hip_runtime.h>
#include <hip/hip_bf16.h>

typedef unsigned short u16;
typedef unsigned int u32;
typedef __attribute__((ext_vector_type(8))) short short8;
typedef __attribute__((ext_vector_type(4))) float f32x4;

__device__ __forceinline__ u16 f2bf(float f) {
    union { float f; unsigned u; } v; v.f = f;
    unsigned r = v.u + 0x7fffu + ((v.u >> 16) & 1u);
    return (u16)(r >> 16);
}

__device__ __forceinline__ float fexp2(float x) {
#if __has_builtin(__builtin_amdgcn_exp2f)
    return __builtin_amdgcn_exp2f(x);
#else
    return __expf(x * 0.6931471805599453f);
#endif
}

// ---------------------------------------------------------------------------
// fp8 e4m3 pack/unpack (P values are pre-scaled x256 so all of [2^-17,1]
// lands in e4m3 normal range -> uniform ~6% rel err; knee-safe).
// ---------------------------------------------------------------------------
#if __has_builtin(__builtin_amdgcn_cvt_pk_fp8_f32) && \
    __has_builtin(__builtin_amdgcn_cvt_f32_fp8)
#define FP8_HW 1
#else
#define FP8_HW 0
#endif

#if !FP8_HW
__device__ __forceinline__ u32 sw_fp8(float x) {  // x in [0, 448]
    union { float f; u32 u; } v; v.f = x;
    int E = (int)(v.u >> 23) - 127;
    if (x < 0.001953125f) return 0;                       // < 2^-9
    if (E < -6) return (u32)(x * 512.0f + 0.5f);          // subnormal
    u32 m = v.u & 0x7fffffu;
    u32 r = (m + 0x80000u) >> 20;
    u32 bits = ((u32)(E + 7) << 3) + r;
    return bits > 0x7eu ? 0x7eu : bits;
}
__device__ __forceinline__ float sw_fp8d(u32 b) {
    u32 e = (b >> 3) & 15u, m = b & 7u;
    if (e == 0) return (float)m * 0.001953125f;
    union { u32 u; float f; } v; v.u = ((e + 120u) << 23) | (m << 20);
    return v.f;
}
#endif

__device__ __forceinline__ u32 fp8x4_pack(float p0, float p1, float p2, float p3) {
#if FP8_HW
    u32 v = (u32)__builtin_amdgcn_cvt_pk_fp8_f32(p0, p1, 0, false);
    v = (u32)__builtin_amdgcn_cvt_pk_fp8_f32(p2, p3, (int)v, true);
    return v;
#else
    return sw_fp8(p0) | (sw_fp8(p1) << 8) | (sw_fp8(p2) << 16) | (sw_fp8(p3) << 24);
#endif
}

#if FP8_HW
#define FP8_DEC(v, s) __builtin_amdgcn_cvt_f32_fp8((int)(v), (s))
#else
#define FP8_DEC(v, s) sw_fp8d(((v) >> ((s) * 8)) & 0xffu)
#endif

// async 16B global->LDS DMA (m97 pattern). lds base must be wave-uniform;
// each lane deposits at base + lane*16.
__device__ __forceinline__ void async_cp16(const u16* g, u16* l) {
    __builtin_amdgcn_global_load_lds(
        (const __attribute__((address_space(1))) void*)g,
        (__attribute__((address_space(3))) void*)l, 16, 0, 0);
}

// ---------------------------------------------------------------------------
// XOR-swizzled LDS GEMM cores (r6: zero SQ_LDS_BANK_CONFLICT).
// Store granule G of each 16-row window at position P = G ^ ((G>>3)&7).
// ---------------------------------------------------------------------------

// 128x128x512: A [128,512] bf16 rm, B^T [128,512] bf16 rm (computes A.B^T).
__device__ __forceinline__ void gemm512(const u16* __restrict__ A,
                                        const u16* __restrict__ B,
                                        u16* As, u16* Bs,
                                        f32x4 acc[4][4], int tid) {
    const int lane = tid & 63, w = tid >> 6;
    const int quad = lane >> 4, l15 = lane & 15;
    const int wm = tid >> 7, wn = (tid >> 6) & 1;
    const int Gw = lane ^ ((lane >> 3) & 7);
    const int srow = Gw >> 2;
    const int scol = (Gw & 3) * 8;
    const int arow0 = w * 32 + srow, arow1 = arow0 + 16;
    u16* la0 = As + (w * 2 + 0) * 512;
    u16* la1 = As + (w * 2 + 1) * 512;
    u16* lb0 = Bs + (w * 2 + 0) * 512;
    u16* lb1 = Bs + (w * 2 + 1) * 512;
    const int Pr8 = ((l15 * 4 + quad) ^ (l15 >> 1)) * 8;
    for (int k0 = 0; k0 < 512; k0 += 32) {
        __syncthreads();
        async_cp16(A + (size_t)arow0 * 512 + k0 + scol, la0);
        async_cp16(A + (size_t)arow1 * 512 + k0 + scol, la1);
        async_cp16(B + (size_t)arow0 * 512 + k0 + scol, lb0);
        async_cp16(B + (size_t)arow1 * 512 + k0 + scol, lb1);
        __syncthreads();
        short8 af[4], bfr[4];
#pragma unroll
        for (int i = 0; i < 4; i++)
            af[i] = *(const short8*)&As[(wm * 64 + i * 16) * 32 + Pr8];
#pragma unroll
        for (int j = 0; j < 4; j++)
            bfr[j] = *(const short8*)&Bs[(wn * 64 + j * 16) * 32 + Pr8];
#pragma unroll
        for (int i = 0; i < 4; i++)
#pragma unroll
            for (int j = 0; j < 4; j++)
                acc[i][j] = __builtin_amdgcn_mfma_f32_16x16x32_bf16(
                    af[i], bfr[j], acc[i][j], 0, 0, 0);
    }
}

// 64x128x512 variant (A 64 rows) for gemm_final.
__device__ __forceinline__ void gemm512_r64(const u16* __restrict__ A,
                                            const u16* __restrict__ B,
                                            u16* As, u16* Bs,
                                            f32x4 acc[2][4], int tid) {
    const int lane = tid & 63, w = tid >> 6;
    const int quad = lane >> 4, l15 = lane & 15;
    const int wm = tid >> 7, wn = (tid >> 6) & 1;
    const int Gw = lane ^ ((lane >> 3) & 7);
    const int srow = Gw >> 2;
    const int scol = (Gw & 3) * 8;
    const int arowA = w * 16 + srow;
    const int arowB0 = (w * 2 + 0) * 16 + srow;
    const int arowB1 = (w * 2 + 1) * 16 + srow;
    u16* la = As + w * 512;
    u16* lb0 = Bs + (w * 2 + 0) * 512;
    u16* lb1 = Bs + (w * 2 + 1) * 512;
    const int Pr8 = ((l15 * 4 + quad) ^ (l15 >> 1)) * 8;
    for (int k0 = 0; k0 < 512; k0 += 32) {
        __syncthreads();
        async_cp16(A + (size_t)arowA * 512 + k0 + scol, la);
        async_cp16(B + (size_t)arowB0 * 512 + k0 + scol, lb0);
        async_cp16(B + (size_t)arowB1 * 512 + k0 + scol, lb1);
        __syncthreads();
        short8 af[2], bfr[4];
#pragma unroll
        for (int i = 0; i < 2; i++)
            af[i] = *(const short8*)&As[(wm * 32 + i * 16) * 32 + Pr8];
#pragma unroll
        for (int j = 0; j < 4; j++)
            bfr[j] = *(const short8*)&Bs[(wn * 64 + j * 16) * 32 + Pr8];
#pragma unroll
        for (int i = 0; i < 2; i++)
#pragma unroll
            for (int j = 0; j < 4; j++)
                acc[i][j] = __builtin_amdgcn_mfma_f32_16x16x32_bf16(
                    af[i], bfr[j], acc[i][j], 0, 0, 0);
    }
}

// ---------------------------------------------------------------------------
// Fused prep: [0,4096) convert X->bf16; [4096,5120) transpose weights;
// 5120: zero Sg + phase-gate counter (graph-safe per-launch reset).
// ---------------------------------------------------------------------------
__global__ void prep(const float* __restrict__ X, const float* __restrict__ W0,
                     const float* __restrict__ W1, const float* __restrict__ W2,
                     const float* __restrict__ W3, u16* __restrict__ Xb,
                     u16* __restrict__ T0, u16* __restrict__ T1,
                     u16* __restrict__ T2, u16* __restrict__ T3,
                     float* __restrict__ Sg, u32* __restrict__ counter) {
    __shared__ float tile[32][33];
    int id = blockIdx.x, tid = threadIdx.x;
    if (id == 5120) {
        if (tid == 0) *counter = 0;
        float4 z = {0.f, 0.f, 0.f, 0.f};
#pragma unroll
        for (int t = 0; t < 8; t++) ((float4*)Sg)[tid + t * 256] = z;
        return;
    }
    if (id < 4096) {
        int idx = (id * 256 + tid) * 4;
        float4 v = *(const float4*)&X[idx];
        ushort4 o;
        o.x = f2bf(v.x); o.y = f2bf(v.y); o.z = f2bf(v.z); o.w = f2bf(v.w);
        *(ushort4*)&Xb[idx] = o;
        return;
    }
    int t = id - 4096;
    int z = t >> 8, rem = t & 255;
    int bo_ = (rem & 15) * 32, bi = (rem >> 4) * 32;
    const float* src; u16* dst;
    switch (z) {
        case 0: src = W0; dst = T0; break;
        case 1: src = W1; dst = T1; break;
        case 2: src = W2; dst = T2; break;
        default: src = W3; dst = T3; break;
    }
    int tx = tid & 31, ty = tid >> 5;
#pragma unroll
    for (int s = 0; s < 4; s++) {
        int i = bi + ty + s * 8;
        tile[ty + s * 8][tx] = src[i * 512 + bo_ + tx];
    }
    __syncthreads();
#pragma unroll
    for (int s = 0; s < 4; s++) {
        int o = bo_ + ty + s * 8;
        dst[o * 512 + bi + tx] = f2bf(tile[tx][ty + s * 8]);
    }
}

// ---------------------------------------------------------------------------
// Fused QKV projection. z==0 (Q) scaled by log2(e) -> base-2 score domain.
// ---------------------------------------------------------------------------
__global__ __launch_bounds__(256) void gemm_qkv(
    const u16* __restrict__ Xb, const u16* __restrict__ Wall,
    const float* __restrict__ bq, const float* __restrict__ bk,
    const float* __restrict__ bv, u16* __restrict__ Qall) {
    __shared__ __align__(16) u16 As[128 * 32];
    __shared__ __align__(16) u16 Bs[128 * 32];
    int tid = threadIdx.x;
    int m0 = blockIdx.x * 128, n0 = blockIdx.y * 128, z = blockIdx.z;
    const u16* Bt = Wall + (size_t)z * 262144 + (size_t)n0 * 512;
    const float* bias = (z == 0) ? bq : (z == 1) ? bk : bv;
    const float qs = (z == 0) ? 1.44269504088896340736f : 1.0f;
    u16* C = Qall + (size_t)z * 4194304;
    f32x4 acc[4][4];
#pragma unroll
    for (int i = 0; i < 4; i++)
#pragma unroll
        for (int j = 0; j < 4; j++) acc[i][j] = (f32x4){0.f, 0.f, 0.f, 0.f};
    gemm512(Xb + (size_t)m0 * 512, Bt, As, Bs, acc, tid);
    int lane = tid & 63, quad = lane >> 4, l15 = lane & 15;
    int wm = tid >> 7, wn = (tid >> 6) & 1;
#pragma unroll
    for (int j = 0; j < 4; j++) {
        int n = n0 + wn * 64 + j * 16 + l15;
        float bvv = bias[n];
#pragma unroll
        for (int i = 0; i < 4; i++)
#pragma unroll
            for (int rg = 0; rg < 4; rg++) {
                int m = m0 + wm * 64 + i * 16 + quad * 4 + rg;
                C[(size_t)m * 512 + n] = f2bf((acc[i][j][rg] + bvv) * qs);
            }
    }
}

// ---------------------------------------------------------------------------
// FUSED ATTENTION (one kernel, software grid barrier):
//  phase1: per block, 2 score tiles (128x128); per-64-col-chunk row-max Mt;
//          P = exp2(s - Mt + 8) packed fp8x4 in REGISTERS (32 VGPRs);
//          (Mt, L/256) -> statsP; Mt also -> LDS.
//  gate:   all 1024 blocks co-resident (launch_bounds(256,4): 4 blk/CU,
//          LDS 18.9KB x4 = 76KB, VGPR<=128) -> device-scope counter spin.
//  phase2: c = M + log2(Z) for own 128 rows (reg-light 2-pass over statsP,
//          L2-hot); column-reduce P * exp2(Mt - 8 - c) -> atomicAdd Sg.
// Removes 68MB P-write + 64MB P-read + 2 kernels vs r8.
// ---------------------------------------------------------------------------
__global__ __launch_bounds__(256, 4) void attn_fused(
    const u16* __restrict__ Qb, const u16* __restrict__ Kb,
    float2* __restrict__ statsP, float* __restrict__ Sg,
    u32* __restrict__ counter) {
    __shared__ __align__(16) u16 As[128 * 32];
    __shared__ __align__(16) u16 Bs[128 * 32];
    __shared__ float mtbuf[2][2][128];
    __shared__ float cbuf[128];
    int tid = threadIdx.x;
    int mblk = blockIdx.x, nch = blockIdx.y, b = blockIdx.z;
    const u16* Q = Qb + ((size_t)(b * 4096 + mblk * 128)) * 512;
    int lane = tid & 63, quad = lane >> 4, l15 = lane & 15;
    int wm = tid >> 7, wn = (tid >> 6) & 1;
    u32 P[2][16];
#pragma unroll
    for (int nt = 0; nt < 2; nt++) {
        const u16* K = Kb + ((size_t)(b * 4096 + nch * 256 + nt * 128)) * 512;
        f32x4 acc[4][4];
#pragma unroll
        for (int i = 0; i < 4; i++)
#pragma unroll
            for (int j = 0; j < 4; j++) acc[i][j] = (f32x4){0.f, 0.f, 0.f, 0.f};
        gemm512(Q, K, As, Bs, acc, tid);
        int ch = nch * 4 + nt * 2 + wn;
#pragma unroll
        for (int i = 0; i < 4; i++)
#pragma unroll
            for (int rg = 0; rg < 4; rg++) {
                float v0 = acc[i][0][rg], v1 = acc[i][1][rg];
                float v2 = acc[i][2][rg], v3 = acc[i][3][rg];
                float Mt = fmaxf(fmaxf(v0, v1), fmaxf(v2, v3));
                Mt = fmaxf(Mt, __shfl_xor(Mt, 1));
                Mt = fmaxf(Mt, __shfl_xor(Mt, 2));
                Mt = fmaxf(Mt, __shfl_xor(Mt, 4));
                Mt = fmaxf(Mt, __shfl_xor(Mt, 8));  // uniform over 16 l15 lanes
                float e8 = Mt - 8.0f;  // x256 pre-scale for fp8 range
                float p0 = fexp2(v0 - e8), p1 = fexp2(v1 - e8);
                float p2 = fexp2(v2 - e8), p3 = fexp2(v3 - e8);
                P[nt][i * 4 + rg] = fp8x4_pack(p0, p1, p2, p3);
                float L = p0 + p1 + p2 + p3;
                L += __shfl_xor(L, 1);
                L += __shfl_xor(L, 2);
                L += __shfl_xor(L, 4);
                L += __shfl_xor(L, 8);
                if (l15 == 0) {
                    int r = wm * 64 + i * 16 + quad * 4 + rg;
                    statsP[((size_t)(b * 64 + ch)) * 4096 + mblk * 128 + r] =
                        make_float2(Mt, L * 0.00390625f);
                    mtbuf[nt][wn][r] = Mt;
                }
            }
    }
    // ---- software grid barrier (all 1024 blocks co-resident) ----
    __syncthreads();
    __threadfence();
    if (tid == 0) {
        __hip_atomic_fetch_add(counter, 1u, __ATOMIC_ACQ_REL,
                               __HIP_MEMORY_SCOPE_AGENT);
        int it = 0;
        while (__hip_atomic_load(counter, __ATOMIC_ACQUIRE,
                                 __HIP_MEMORY_SCOPE_AGENT) < 1024u &&
               it < (1 << 24)) {
            __builtin_amdgcn_s_sleep(2);
            ++it;
        }
    }
    __syncthreads();
    // ---- phase2: global row norms for this block's 128 rows ----
    if (tid < 128) {
        const float2* sp = statsP + (size_t)b * 64 * 4096 + mblk * 128 + tid;
        float M = -INFINITY;
#pragma unroll 4
        for (int c2 = 0; c2 < 64; c2++) M = fmaxf(M, sp[(size_t)c2 * 4096].x);
        float Z = 0.f;
#pragma unroll 4
        for (int c2 = 0; c2 < 64; c2++) {
            float2 p = sp[(size_t)c2 * 4096];
            Z += p.y * fexp2(p.x - M);
        }
        cbuf[tid] = M + __log2f(Z);
    }
    __syncthreads();
    // ---- column partial sums from register-resident fp8 P ----
    float cp[2][4];
#pragma unroll
    for (int nt = 0; nt < 2; nt++)
#pragma unroll
        for (int j = 0; j < 4; j++) cp[nt][j] = 0.f;
#pragma unroll
    for (int nt = 0; nt < 2; nt++)
#pragma unroll
        for (int i = 0; i < 4; i++)
#pragma unroll
            for (int rg = 0; rg < 4; rg++) {
                int r = wm * 64 + i * 16 + quad * 4 + rg;
                float F = fexp2(mtbuf[nt][wn][r] - 8.0f - cbuf[r]);
                u32 e = P[nt][i * 4 + rg];
                cp[nt][0] += FP8_DEC(e, 0) * F;
                cp[nt][1] += FP8_DEC(e, 1) * F;
                cp[nt][2] += FP8_DEC(e, 2) * F;
                cp[nt][3] += FP8_DEC(e, 3) * F;
            }
#pragma unroll
    for (int nt = 0; nt < 2; nt++)
#pragma unroll
        for (int j = 0; j < 4; j++) {
            float s = cp[nt][j];
            s += __shfl_xor(s, 16);
            s += __shfl_xor(s, 32);
            if (lane < 16)
                atomicAdd(&Sg[b * 4096 + nch * 256 + nt * 128 + wn * 64 +
                              j * 16 + lane],
                          s);
        }
}

// ---------------------------------------------------------------------------
// Final: out = relu(BN((V*rowscale) . Wo^T + bo)) + X  (fp32 out)
// 64x128 tiles, grid (128, 4). m0 in [0,8192) == flat (b,m).
// ---------------------------------------------------------------------------
__global__ __launch_bounds__(256) void gemm_final(
    const u16* __restrict__ A, const u16* __restrict__ Bt,
    const float* __restrict__ Sg, const float* __restrict__ bo,
    const float* __restrict__ g, const float* __restrict__ bb,
    const float* __restrict__ mean, const float* __restrict__ var,
    const float* __restrict__ X, float* __restrict__ out) {
    __shared__ __align__(16) u16 As[64 * 32];
    __shared__ __align__(16) u16 Bs[128 * 32];
    int tid = threadIdx.x;
    int m0 = blockIdx.x * 64, n0 = blockIdx.y * 128;
    f32x4 acc[2][4];
#pragma unroll
    for (int i = 0; i < 2; i++)
#pragma unroll
        for (int j = 0; j < 4; j++) acc[i][j] = (f32x4){0.f, 0.f, 0.f, 0.f};
    gemm512_r64(A + (size_t)m0 * 512, Bt + (size_t)n0 * 512, As, Bs, acc, tid);
    int lane = tid & 63, quad = lane >> 4, l15 = lane & 15;
    int wm = tid >> 7, wn = (tid >> 6) & 1;
    float sc[2][4];
#pragma unroll
    for (int i = 0; i < 2; i++) {
        float4 s = *(const float4*)&Sg[m0 + wm * 32 + i * 16 + quad * 4];
        float v[4] = {s.x, s.y, s.z, s.w};
#pragma unroll
        for (int rg = 0; rg < 4; rg++) sc[i][rg] = v[rg] / (1e-9f + v[rg]);
    }
#pragma unroll
    for (int j = 0; j < 4; j++) {
        int n = n0 + wn * 64 + j * 16 + l15;
        float aj = rsqrtf(var[n] + 1e-5f) * g[n];
        float cj = bb[n] - mean[n] * aj;
        float bj = bo[n];
#pragma unroll
        for (int i = 0; i < 2; i++)
#pragma unroll
            for (int rg = 0; rg < 4; rg++) {
                int m = m0 + wm * 32 + i * 16 + quad * 4 + rg;
                float x = acc[i][j][rg] * sc[i][rg] + bj;
                float y = x * aj + cj;
                out[(size_t)m * 512 + n] = fmaxf(y, 0.f) + X[(size_t)m * 512 + n];
            }
    }
}

// ---------------------------------------------------------------------------
extern "C" void kernel_launch(void* const* d_in, const int* in_sizes, int n_in,
                              void* d_out, int out_size, void* d_ws, size_t ws_size,
                              hipStream_t stream) {
    const float* X  = (const float*)d_in[0];
    const float* Wq = (const float*)d_in[1];
    const float* Wk = (const float*)d_in[2];
    const float* Wv = (const float*)d_in[3];
    const float* Wo = (const float*)d_in[4];
    const float* bq = (const float*)d_in[5];
    const float* bk = (const float*)d_in[6];
    const float* bv = (const float*)d_in[7];
    const float* bo = (const float*)d_in[8];
    const float* g    = (const float*)d_in[9];
    const float* bb   = (const float*)d_in[10];
    const float* mean = (const float*)d_in[11];
    const float* var  = (const float*)d_in[12];
    float* out = (float*)d_out;

    char* ws = (char*)d_ws;
    u16* Xb  = (u16*)(ws + 0);                    // 8 MB
    u16* Wqt = (u16*)(ws + 8388608);              // 4x512KB (Wq,Wk,Wv,Wo)
    u16* Wot = (u16*)(ws + 9961472);
    u16* Qb  = (u16*)(ws + 10485760);             // Q,K,V contiguous 3x8MB
    u16* Kb  = (u16*)(ws + 18874368);
    u16* Vb  = (u16*)(ws + 27262976);
    float2* statsP = (float2*)(ws + 35651584);    // [b][64][4096] f2 = 4 MB
    float* Sg      = (float*)(ws + 39845888);     // 32 KB
    u32* counter   = (u32*)(ws + 39878656);       // 4 B  (total ~40 MB)

    prep<<<5121, 256, 0, stream>>>(X, Wq, Wk, Wv, Wo, Xb, Wqt, Wqt + 262144,
                                   Wqt + 524288, Wot, Sg, counter);
    gemm_qkv<<<dim3(64, 4, 3), 256, 0, stream>>>(Xb, Wqt, bq, bk, bv, Qb);
    attn_fused<<<dim3(32, 16, 2), 256, 0, stream>>>(Qb, Kb, statsP, Sg, counter);
    gemm_final<<<dim3(128, 4), 256, 0, stream>>>(Vb, Wot, Sg, bo, g, bb, mean, var,
                                                 X, out);
}

// Round 10
// 232.466 us; speedup vs baseline: 1.6067x; 1.6067x over previous
//
#include <hip/hip_runtime.h>
#include <hip/hip_bf16.h>

typedef unsigned short u16;
typedef unsigned int u32;
typedef __attribute__((ext_vector_type(8))) short short8;
typedef __attribute__((ext_vector_type(4))) float f32x4;

__device__ __forceinline__ u16 f2bf(float f) {
    union { float f; unsigned u; } v; v.f = f;
    unsigned r = v.u + 0x7fffu + ((v.u >> 16) & 1u);
    return (u16)(r >> 16);
}

__device__ __forceinline__ float fexp2(float x) {
#if __has_builtin(__builtin_amdgcn_exp2f)
    return __builtin_amdgcn_exp2f(x);
#else
    return __expf(x * 0.6931471805599453f);
#endif
}

// ---------------------------------------------------------------------------
// fp8 e4m3 pack/unpack (P pre-scaled x256 so [2^-17,1] is normal range;
// ~6% rel err -> scale err <=1.5% at the EPS knee; r9 measured absmax 0.078).
// ---------------------------------------------------------------------------
#if __has_builtin(__builtin_amdgcn_cvt_pk_fp8_f32) && \
    __has_builtin(__builtin_amdgcn_cvt_f32_fp8)
#define FP8_HW 1
#else
#define FP8_HW 0
#endif

#if !FP8_HW
__device__ __forceinline__ u32 sw_fp8(float x) {  // x in [0, 448]
    union { float f; u32 u; } v; v.f = x;
    int E = (int)(v.u >> 23) - 127;
    if (x < 0.001953125f) return 0;                       // < 2^-9
    if (E < -6) return (u32)(x * 512.0f + 0.5f);          // subnormal
    u32 m = v.u & 0x7fffffu;
    u32 r = (m + 0x80000u) >> 20;
    u32 bits = ((u32)(E + 7) << 3) + r;
    return bits > 0x7eu ? 0x7eu : bits;
}
__device__ __forceinline__ float sw_fp8d(u32 b) {
    u32 e = (b >> 3) & 15u, m = b & 7u;
    if (e == 0) return (float)m * 0.001953125f;
    union { u32 u; float f; } v; v.u = ((e + 120u) << 23) | (m << 20);
    return v.f;
}
#endif

__device__ __forceinline__ u32 fp8x4_pack(float p0, float p1, float p2, float p3) {
#if FP8_HW
    u32 v = (u32)__builtin_amdgcn_cvt_pk_fp8_f32(p0, p1, 0, false);
    v = (u32)__builtin_amdgcn_cvt_pk_fp8_f32(p2, p3, (int)v, true);
    return v;
#else
    return sw_fp8(p0) | (sw_fp8(p1) << 8) | (sw_fp8(p2) << 16) | (sw_fp8(p3) << 24);
#endif
}

#if FP8_HW
#define FP8_DEC(v, s) __builtin_amdgcn_cvt_f32_fp8((int)(v), (s))
#else
#define FP8_DEC(v, s) sw_fp8d(((v) >> ((s) * 8)) & 0xffu)
#endif

// async 16B global->LDS DMA (m97 pattern). lds base must be wave-uniform;
// each lane deposits at base + lane*16.
__device__ __forceinline__ void async_cp16(const u16* g, u16* l) {
    __builtin_amdgcn_global_load_lds(
        (const __attribute__((address_space(1))) void*)g,
        (__attribute__((address_space(3))) void*)l, 16, 0, 0);
}

// ---------------------------------------------------------------------------
// XOR-swizzled LDS GEMM cores (r6: zero SQ_LDS_BANK_CONFLICT).
// Store granule G of each 16-row window at position P = G ^ ((G>>3)&7).
// ---------------------------------------------------------------------------

// 128x128x512: A [128,512] bf16 rm, B^T [128,512] bf16 rm (computes A.B^T).
__device__ __forceinline__ void gemm512(const u16* __restrict__ A,
                                        const u16* __restrict__ B,
                                        u16* As, u16* Bs,
                                        f32x4 acc[4][4], int tid) {
    const int lane = tid & 63, w = tid >> 6;
    const int quad = lane >> 4, l15 = lane & 15;
    const int wm = tid >> 7, wn = (tid >> 6) & 1;
    const int Gw = lane ^ ((lane >> 3) & 7);
    const int srow = Gw >> 2;
    const int scol = (Gw & 3) * 8;
    const int arow0 = w * 32 + srow, arow1 = arow0 + 16;
    u16* la0 = As + (w * 2 + 0) * 512;
    u16* la1 = As + (w * 2 + 1) * 512;
    u16* lb0 = Bs + (w * 2 + 0) * 512;
    u16* lb1 = Bs + (w * 2 + 1) * 512;
    const int Pr8 = ((l15 * 4 + quad) ^ (l15 >> 1)) * 8;
    for (int k0 = 0; k0 < 512; k0 += 32) {
        __syncthreads();
        async_cp16(A + (size_t)arow0 * 512 + k0 + scol, la0);
        async_cp16(A + (size_t)arow1 * 512 + k0 + scol, la1);
        async_cp16(B + (size_t)arow0 * 512 + k0 + scol, lb0);
        async_cp16(B + (size_t)arow1 * 512 + k0 + scol, lb1);
        __syncthreads();
        short8 af[4], bfr[4];
#pragma unroll
        for (int i = 0; i < 4; i++)
            af[i] = *(const short8*)&As[(wm * 64 + i * 16) * 32 + Pr8];
#pragma unroll
        for (int j = 0; j < 4; j++)
            bfr[j] = *(const short8*)&Bs[(wn * 64 + j * 16) * 32 + Pr8];
#pragma unroll
        for (int i = 0; i < 4; i++)
#pragma unroll
            for (int j = 0; j < 4; j++)
                acc[i][j] = __builtin_amdgcn_mfma_f32_16x16x32_bf16(
                    af[i], bfr[j], acc[i][j], 0, 0, 0);
    }
}

// 64x128x512 variant (A 64 rows) for gemm_final.
__device__ __forceinline__ void gemm512_r64(const u16* __restrict__ A,
                                            const u16* __restrict__ B,
                                            u16* As, u16* Bs,
                                            f32x4 acc[2][4], int tid) {
    const int lane = tid & 63, w = tid >> 6;
    const int quad = lane >> 4, l15 = lane & 15;
    const int wm = tid >> 7, wn = (tid >> 6) & 1;
    const int Gw = lane ^ ((lane >> 3) & 7);
    const int srow = Gw >> 2;
    const int scol = (Gw & 3) * 8;
    const int arowA = w * 16 + srow;
    const int arowB0 = (w * 2 + 0) * 16 + srow;
    const int arowB1 = (w * 2 + 1) * 16 + srow;
    u16* la = As + w * 512;
    u16* lb0 = Bs + (w * 2 + 0) * 512;
    u16* lb1 = Bs + (w * 2 + 1) * 512;
    const int Pr8 = ((l15 * 4 + quad) ^ (l15 >> 1)) * 8;
    for (int k0 = 0; k0 < 512; k0 += 32) {
        __syncthreads();
        async_cp16(A + (size_t)arowA * 512 + k0 + scol, la);
        async_cp16(B + (size_t)arowB0 * 512 + k0 + scol, lb0);
        async_cp16(B + (size_t)arowB1 * 512 + k0 + scol, lb1);
        __syncthreads();
        short8 af[2], bfr[4];
#pragma unroll
        for (int i = 0; i < 2; i++)
            af[i] = *(const short8*)&As[(wm * 32 + i * 16) * 32 + Pr8];
#pragma unroll
        for (int j = 0; j < 4; j++)
            bfr[j] = *(const short8*)&Bs[(wn * 64 + j * 16) * 32 + Pr8];
#pragma unroll
        for (int i = 0; i < 2; i++)
#pragma unroll
            for (int j = 0; j < 4; j++)
                acc[i][j] = __builtin_amdgcn_mfma_f32_16x16x32_bf16(
                    af[i], bfr[j], acc[i][j], 0, 0, 0);
    }
}

// ---------------------------------------------------------------------------
// Fused prep: [0,4096) convert X->bf16; [4096,5120) transpose weights;
// 5120: zero Sg (per-launch, graph-safe).
// ---------------------------------------------------------------------------
__global__ void prep(const float* __restrict__ X, const float* __restrict__ W0,
                     const float* __restrict__ W1, const float* __restrict__ W2,
                     const float* __restrict__ W3, u16* __restrict__ Xb,
                     u16* __restrict__ T0, u16* __restrict__ T1,
                     u16* __restrict__ T2, u16* __restrict__ T3,
                     float* __restrict__ Sg) {
    __shared__ float tile[32][33];
    int id = blockIdx.x, tid = threadIdx.x;
    if (id == 5120) {
        float4 z = {0.f, 0.f, 0.f, 0.f};
#pragma unroll
        for (int t = 0; t < 8; t++) ((float4*)Sg)[tid + t * 256] = z;
        return;
    }
    if (id < 4096) {
        int idx = (id * 256 + tid) * 4;
        float4 v = *(const float4*)&X[idx];
        ushort4 o;
        o.x = f2bf(v.x); o.y = f2bf(v.y); o.z = f2bf(v.z); o.w = f2bf(v.w);
        *(ushort4*)&Xb[idx] = o;
        return;
    }
    int t = id - 4096;
    int z = t >> 8, rem = t & 255;
    int bo_ = (rem & 15) * 32, bi = (rem >> 4) * 32;
    const float* src; u16* dst;
    switch (z) {
        case 0: src = W0; dst = T0; break;
        case 1: src = W1; dst = T1; break;
        case 2: src = W2; dst = T2; break;
        default: src = W3; dst = T3; break;
    }
    int tx = tid & 31, ty = tid >> 5;
#pragma unroll
    for (int s = 0; s < 4; s++) {
        int i = bi + ty + s * 8;
        tile[ty + s * 8][tx] = src[i * 512 + bo_ + tx];
    }
    __syncthreads();
#pragma unroll
    for (int s = 0; s < 4; s++) {
        int o = bo_ + ty + s * 8;
        dst[o * 512 + bi + tx] = f2bf(tile[tx][ty + s * 8]);
    }
}

// ---------------------------------------------------------------------------
// Fused QKV projection. z==0 (Q) scaled by log2(e) -> base-2 score domain.
// ---------------------------------------------------------------------------
__global__ __launch_bounds__(256) void gemm_qkv(
    const u16* __restrict__ Xb, const u16* __restrict__ Wall,
    const float* __restrict__ bq, const float* __restrict__ bk,
    const float* __restrict__ bv, u16* __restrict__ Qall) {
    __shared__ __align__(16) u16 As[128 * 32];
    __shared__ __align__(16) u16 Bs[128 * 32];
    int tid = threadIdx.x;
    int m0 = blockIdx.x * 128, n0 = blockIdx.y * 128, z = blockIdx.z;
    const u16* Bt = Wall + (size_t)z * 262144 + (size_t)n0 * 512;
    const float* bias = (z == 0) ? bq : (z == 1) ? bk : bv;
    const float qs = (z == 0) ? 1.44269504088896340736f : 1.0f;
    u16* C = Qall + (size_t)z * 4194304;
    f32x4 acc[4][4];
#pragma unroll
    for (int i = 0; i < 4; i++)
#pragma unroll
        for (int j = 0; j < 4; j++) acc[i][j] = (f32x4){0.f, 0.f, 0.f, 0.f};
    gemm512(Xb + (size_t)m0 * 512, Bt, As, Bs, acc, tid);
    int lane = tid & 63, quad = lane >> 4, l15 = lane & 15;
    int wm = tid >> 7, wn = (tid >> 6) & 1;
#pragma unroll
    for (int j = 0; j < 4; j++) {
        int n = n0 + wn * 64 + j * 16 + l15;
        float bvv = bias[n];
#pragma unroll
        for (int i = 0; i < 4; i++)
#pragma unroll
            for (int rg = 0; rg < 4; rg++) {
                int m = m0 + wm * 64 + i * 16 + quad * 4 + rg;
                C[(size_t)m * 512 + n] = f2bf((acc[i][j][rg] + bvv) * qs);
            }
    }
}

// ---------------------------------------------------------------------------
// Pass 1, fp8 P-store: per 128x128 score tile, per-64-col-chunk row-max Mt;
// P = exp2(s - Mt + 8) packed fp8x4 (1 u32 per 4 values), value-major
// [g][tid] (coalesced); stats (Mt, L). Epilogue writes straight out — no
// cross-barrier register state (r9 spill lesson). grid (32, 16, 2).
// ---------------------------------------------------------------------------
__global__ __launch_bounds__(256) void attn_pass1p(
    const u16* __restrict__ Qb, const u16* __restrict__ Kb,
    float2* __restrict__ statsP, u32* __restrict__ Pbuf) {
    __shared__ __align__(16) u16 As[128 * 32];
    __shared__ __align__(16) u16 Bs[128 * 32];
    int tid = threadIdx.x;
    int mblk = blockIdx.x, nch = blockIdx.y, b = blockIdx.z;
    const u16* Q = Qb + ((size_t)(b * 4096 + mblk * 128)) * 512;
    int lane = tid & 63, quad = lane >> 4, l15 = lane & 15;
    int wm = tid >> 7, wn = (tid >> 6) & 1;
    for (int nt = 0; nt < 2; nt++) {
        const u16* K = Kb + ((size_t)(b * 4096 + nch * 256 + nt * 128)) * 512;
        f32x4 acc[4][4];
#pragma unroll
        for (int i = 0; i < 4; i++)
#pragma unroll
            for (int j = 0; j < 4; j++) acc[i][j] = (f32x4){0.f, 0.f, 0.f, 0.f};
        gemm512(Q, K, As, Bs, acc, tid);
        u32* Pt = Pbuf + (((size_t)(b * 32 + mblk) * 16 + nch) * 2 + nt) * 4096;
        int ch = nch * 4 + nt * 2 + wn;
#pragma unroll
        for (int i = 0; i < 4; i++)
#pragma unroll
            for (int rg = 0; rg < 4; rg++) {
                float v0 = acc[i][0][rg], v1 = acc[i][1][rg];
                float v2 = acc[i][2][rg], v3 = acc[i][3][rg];
                float Mt = fmaxf(fmaxf(v0, v1), fmaxf(v2, v3));
                Mt = fmaxf(Mt, __shfl_xor(Mt, 1));
                Mt = fmaxf(Mt, __shfl_xor(Mt, 2));
                Mt = fmaxf(Mt, __shfl_xor(Mt, 4));
                Mt = fmaxf(Mt, __shfl_xor(Mt, 8));  // uniform over 16 l15 lanes
                float e8 = Mt - 8.0f;  // x256 pre-scale for fp8 range
                float p0 = fexp2(v0 - e8), p1 = fexp2(v1 - e8);
                float p2 = fexp2(v2 - e8), p3 = fexp2(v3 - e8);
                Pt[(i * 4 + rg) * 256 + tid] = fp8x4_pack(p0, p1, p2, p3);
                float L = p0 + p1 + p2 + p3;
                L += __shfl_xor(L, 1);
                L += __shfl_xor(L, 2);
                L += __shfl_xor(L, 4);
                L += __shfl_xor(L, 8);
                if (l15 == 0)
                    statsP[((size_t)(b * 64 + ch)) * 4096 + mblk * 128 +
                           wm * 64 + i * 16 + quad * 4 + rg] =
                        make_float2(Mt, L * 0.00390625f);  // true L_ch
            }
    }
}

// ---------------------------------------------------------------------------
// Fused c-compute + weighted column sums (replaces reduce_stats2 + colsum):
// phase A: c = M + log2(Z) for this block's 512 rows (reg-light 2-pass over
// L2-hot statsP; r7's spill lesson) -> LDS cbuf.
// phase B: S[n] += sum_m P_fp8[m,n] * exp2(Mt[m] - 8 - c[m]).
// grid (nch=16, y = nt + 2*mgrp (8 mgrps of 4 mblks), b=2) = 512 blocks.
// ---------------------------------------------------------------------------
__global__ __launch_bounds__(256) void colsum_fused(
    const u32* __restrict__ Pbuf, const float2* __restrict__ statsP,
    float* __restrict__ Sg) {
    __shared__ float cbuf[512];
    int tid = threadIdx.x, lane = tid & 63;
    int wm = tid >> 7, wn = (tid >> 6) & 1, quad = lane >> 4;
    int nch = blockIdx.x, nt = blockIdx.y & 1, mgrp = blockIdx.y >> 1;
    int b = blockIdx.z;
    int ch = nch * 4 + nt * 2 + wn;
    // phase A: row norms for rows [mgrp*512, mgrp*512+512)
#pragma unroll
    for (int h = 0; h < 2; h++) {
        int row = mgrp * 512 + h * 256 + tid;
        const float2* sp = statsP + (size_t)b * 64 * 4096 + row;
        float M = -INFINITY;
#pragma unroll 4
        for (int c2 = 0; c2 < 64; c2++) M = fmaxf(M, sp[(size_t)c2 * 4096].x);
        float Z = 0.f;
#pragma unroll 4
        for (int c2 = 0; c2 < 64; c2++) {
            float2 p = sp[(size_t)c2 * 4096];
            Z += p.y * fexp2(p.x - M);
        }
        cbuf[h * 256 + tid] = M + __log2f(Z);
    }
    __syncthreads();
    // phase B: weighted column sums over 4 mblk tiles
    const float2* Sp = statsP + ((size_t)(b * 64 + ch)) * 4096;
    float cp[4] = {0.f, 0.f, 0.f, 0.f};
    for (int mb = 0; mb < 4; mb++) {
        int mblk = mgrp * 4 + mb;
        const u32* Pt =
            Pbuf + (((size_t)(b * 32 + mblk) * 16 + nch) * 2 + nt) * 4096;
#pragma unroll
        for (int i = 0; i < 4; i++) {
            int r0 = mblk * 128 + wm * 64 + i * 16 + quad * 4;
            float4 s01 = *(const float4*)&Sp[r0];      // (M0,L0,M1,L1)
            float4 s23 = *(const float4*)&Sp[r0 + 2];  // (M2,L2,M3,L3)
            float4 cv = *(const float4*)&cbuf[r0 - mgrp * 512];
            float fv[4] = {fexp2(s01.x - 8.0f - cv.x),
                           fexp2(s01.z - 8.0f - cv.y),
                           fexp2(s23.x - 8.0f - cv.z),
                           fexp2(s23.z - 8.0f - cv.w)};
#pragma unroll
            for (int rg = 0; rg < 4; rg++) {
                u32 e = Pt[(i * 4 + rg) * 256 + tid];
                cp[0] += FP8_DEC(e, 0) * fv[rg];
                cp[1] += FP8_DEC(e, 1) * fv[rg];
                cp[2] += FP8_DEC(e, 2) * fv[rg];
                cp[3] += FP8_DEC(e, 3) * fv[rg];
            }
        }
    }
#pragma unroll
    for (int j = 0; j < 4; j++) {
        float s = cp[j];
        s += __shfl_xor(s, 16);
        s += __shfl_xor(s, 32);
        if (lane < 16)
            atomicAdd(&Sg[b * 4096 + nch * 256 + nt * 128 + wn * 64 + j * 16 + lane], s);
    }
}

// ---------------------------------------------------------------------------
// LEGACY fallback (round-6 flow) if ws_size can't hold Pbuf.
// ---------------------------------------------------------------------------
__global__ __launch_bounds__(256) void legacy_pass1(
    const u16* __restrict__ Qb, const u16* __restrict__ Kb,
    float2* __restrict__ statsP) {
    __shared__ __align__(16) u16 As[128 * 32];
    __shared__ __align__(16) u16 Bs[128 * 32];
    int tid = threadIdx.x;
    int mblk = blockIdx.x, nch = blockIdx.y, b = blockIdx.z;
    const u16* Q = Qb + ((size_t)(b * 4096 + mblk * 128)) * 512;
    int lane = tid & 63, quad = lane >> 4, l15 = lane & 15;
    int wm = tid >> 7, wn = (tid >> 6) & 1;
    float runM[4][4], runL[4][4];
#pragma unroll
    for (int i = 0; i < 4; i++)
#pragma unroll
        for (int rg = 0; rg < 4; rg++) { runM[i][rg] = -INFINITY; runL[i][rg] = 0.f; }
    for (int nt = 0; nt < 2; nt++) {
        const u16* K = Kb + ((size_t)(b * 4096 + nch * 256 + nt * 128)) * 512;
        f32x4 acc[4][4];
#pragma unroll
        for (int i = 0; i < 4; i++)
#pragma unroll
            for (int j = 0; j < 4; j++) acc[i][j] = (f32x4){0.f, 0.f, 0.f, 0.f};
        gemm512(Q, K, As, Bs, acc, tid);
#pragma unroll
        for (int i = 0; i < 4; i++)
#pragma unroll
            for (int rg = 0; rg < 4; rg++) {
                float v0 = acc[i][0][rg], v1 = acc[i][1][rg];
                float v2 = acc[i][2][rg], v3 = acc[i][3][rg];
                float vm = fmaxf(fmaxf(v0, v1), fmaxf(v2, v3));
                float mo = runM[i][rg];
                if (vm > mo - 30.f) {
                    float nm = fmaxf(mo, vm);
                    runL[i][rg] = runL[i][rg] * fexp2(mo - nm) +
                                  fexp2(v0 - nm) + fexp2(v1 - nm) +
                                  fexp2(v2 - nm) + fexp2(v3 - nm);
                    runM[i][rg] = nm;
                }
            }
    }
#pragma unroll
    for (int i = 0; i < 4; i++)
#pragma unroll
        for (int rg = 0; rg < 4; rg++) {
            float M = runM[i][rg];
            float Mf = M;
#pragma unroll
            for (int d = 1; d < 16; d <<= 1) Mf = fmaxf(Mf, __shfl_xor(Mf, d));
            float L = runL[i][rg] * fexp2(M - Mf);
#pragma unroll
            for (int d = 1; d < 16; d <<= 1) L += __shfl_xor(L, d);
            if (l15 == 0)
                statsP[((size_t)(b * 32 + nch * 2 + wn)) * 4096 +
                       mblk * 128 + wm * 64 + i * 16 + quad * 4 + rg] =
                    make_float2(Mf, L);
        }
}

__global__ void legacy_reduce(const float2* __restrict__ statsP,
                              float* __restrict__ cstat, float* __restrict__ Sg) {
    int t = blockIdx.x * 256 + threadIdx.x;
    int b = t >> 12, m = t & 4095;
    const float2* sp = statsP + (size_t)b * 32 * 4096 + m;
    float M = -INFINITY;
#pragma unroll 4
    for (int ch = 0; ch < 32; ch++) M = fmaxf(M, sp[(size_t)ch * 4096].x);
    float L = 0.f;
#pragma unroll 4
    for (int ch = 0; ch < 32; ch++) {
        float2 p = sp[(size_t)ch * 4096];
        L += p.y * fexp2(p.x - M);
    }
    cstat[t] = M + __log2f(L);
    Sg[t] = 0.f;
}

__global__ __launch_bounds__(256) void legacy_pass2(
    const u16* __restrict__ Qb, const u16* __restrict__ Kb,
    const float* __restrict__ cstat, float* __restrict__ Sg) {
    __shared__ __align__(16) u16 As[128 * 32];
    __shared__ __align__(16) u16 Bs[128 * 32];
    int tid = threadIdx.x;
    int nblk = blockIdx.x, mch = blockIdx.y, b = blockIdx.z;
    const u16* K = Kb + ((size_t)(b * 4096 + nblk * 128)) * 512;
    int lane = tid & 63, quad = lane >> 4;
    int wm = tid >> 7, wn = (tid >> 6) & 1;
    float cp0 = 0.f, cp1 = 0.f, cp2 = 0.f, cp3 = 0.f;
    for (int mt = 0; mt < 2; mt++) {
        int m0 = mch * 256 + mt * 128;
        const u16* Q = Qb + ((size_t)(b * 4096 + m0)) * 512;
        f32x4 acc[4][4];
#pragma unroll
        for (int i = 0; i < 4; i++)
#pragma unroll
            for (int j = 0; j < 4; j++) acc[i][j] = (f32x4){0.f, 0.f, 0.f, 0.f};
        gemm512(Q, K, As, Bs, acc, tid);
        float4 c4[4];
#pragma unroll
        for (int i = 0; i < 4; i++)
            c4[i] = *(const float4*)&cstat[b * 4096 + m0 + wm * 64 + i * 16 + quad * 4];
#pragma unroll
        for (int i = 0; i < 4; i++) {
            float cc[4] = {c4[i].x, c4[i].y, c4[i].z, c4[i].w};
#pragma unroll
            for (int rg = 0; rg < 4; rg++) {
                float c = cc[rg];
                float v0 = acc[i][0][rg] - c, v1 = acc[i][1][rg] - c;
                float v2 = acc[i][2][rg] - c, v3 = acc[i][3][rg] - c;
                float vm = fmaxf(fmaxf(v0, v1), fmaxf(v2, v3));
                if (vm > -60.f) {
                    cp0 += fexp2(v0); cp1 += fexp2(v1);
                    cp2 += fexp2(v2); cp3 += fexp2(v3);
                }
            }
        }
    }
    float cps[4] = {cp0, cp1, cp2, cp3};
#pragma unroll
    for (int j = 0; j < 4; j++) {
        float s = cps[j];
        s += __shfl_xor(s, 16);
        s += __shfl_xor(s, 32);
        if (lane < 16)
            atomicAdd(&Sg[b * 4096 + nblk * 128 + wn * 64 + j * 16 + lane], s);
    }
}

// ---------------------------------------------------------------------------
// Final: out = relu(BN((V*rowscale) . Wo^T + bo)) + X  (fp32 out)
// 64x128 tiles, grid (128, 4). m0 in [0,8192) == flat (b,m).
// ---------------------------------------------------------------------------
__global__ __launch_bounds__(256) void gemm_final(
    const u16* __restrict__ A, const u16* __restrict__ Bt,
    const float* __restrict__ Sg, const float* __restrict__ bo,
    const float* __restrict__ g, const float* __restrict__ bb,
    const float* __restrict__ mean, const float* __restrict__ var,
    const float* __restrict__ X, float* __restrict__ out) {
    __shared__ __align__(16) u16 As[64 * 32];
    __shared__ __align__(16) u16 Bs[128 * 32];
    int tid = threadIdx.x;
    int m0 = blockIdx.x * 64, n0 = blockIdx.y * 128;
    f32x4 acc[2][4];
#pragma unroll
    for (int i = 0; i < 2; i++)
#pragma unroll
        for (int j = 0; j < 4; j++) acc[i][j] = (f32x4){0.f, 0.f, 0.f, 0.f};
    gemm512_r64(A + (size_t)m0 * 512, Bt + (size_t)n0 * 512, As, Bs, acc, tid);
    int lane = tid & 63, quad = lane >> 4, l15 = lane & 15;
    int wm = tid >> 7, wn = (tid >> 6) & 1;
    float sc[2][4];
#pragma unroll
    for (int i = 0; i < 2; i++) {
        float4 s = *(const float4*)&Sg[m0 + wm * 32 + i * 16 + quad * 4];
        float v[4] = {s.x, s.y, s.z, s.w};
#pragma unroll
        for (int rg = 0; rg < 4; rg++) sc[i][rg] = v[rg] / (1e-9f + v[rg]);
    }
#pragma unroll
    for (int j = 0; j < 4; j++) {
        int n = n0 + wn * 64 + j * 16 + l15;
        float aj = rsqrtf(var[n] + 1e-5f) * g[n];
        float cj = bb[n] - mean[n] * aj;
        float bj = bo[n];
#pragma unroll
        for (int i = 0; i < 2; i++)
#pragma unroll
            for (int rg = 0; rg < 4; rg++) {
                int m = m0 + wm * 32 + i * 16 + quad * 4 + rg;
                float x = acc[i][j][rg] * sc[i][rg] + bj;
                float y = x * aj + cj;
                out[(size_t)m * 512 + n] = fmaxf(y, 0.f) + X[(size_t)m * 512 + n];
            }
    }
}

// ---------------------------------------------------------------------------
extern "C" void kernel_launch(void* const* d_in, const int* in_sizes, int n_in,
                              void* d_out, int out_size, void* d_ws, size_t ws_size,
                              hipStream_t stream) {
    const float* X  = (const float*)d_in[0];
    const float* Wq = (const float*)d_in[1];
    const float* Wk = (const float*)d_in[2];
    const float* Wv = (const float*)d_in[3];
    const float* Wo = (const float*)d_in[4];
    const float* bq = (const float*)d_in[5];
    const float* bk = (const float*)d_in[6];
    const float* bv = (const float*)d_in[7];
    const float* bo = (const float*)d_in[8];
    const float* g    = (const float*)d_in[9];
    const float* bb   = (const float*)d_in[10];
    const float* mean = (const float*)d_in[11];
    const float* var  = (const float*)d_in[12];
    float* out = (float*)d_out;

    char* ws = (char*)d_ws;
    u16* Xb  = (u16*)(ws + 0);                    // 8 MB
    u16* Wqt = (u16*)(ws + 8388608);              // 4x512KB (Wq,Wk,Wv,Wo)
    u16* Wot = (u16*)(ws + 9961472);
    u16* Qb  = (u16*)(ws + 10485760);             // Q,K,V contiguous 3x8MB
    u16* Kb  = (u16*)(ws + 18874368);
    u16* Vb  = (u16*)(ws + 27262976);
    float2* statsP = (float2*)(ws + 35651584);    // [b][64][4096] f2 = 4 MB
    float* Sg      = (float*)(ws + 39845888);     // 32 KB
    float* cstat   = (float*)(ws + 39878656);     // 32 KB (legacy)
    u32* Pbuf      = (u32*)(ws + 39911424);       // 32 MB fp8 P

    const size_t FULL_NEED = 39911424ull + 33554432ull;  // ~70 MB

    prep<<<5121, 256, 0, stream>>>(X, Wq, Wk, Wv, Wo, Xb, Wqt, Wqt + 262144,
                                   Wqt + 524288, Wot, Sg);
    gemm_qkv<<<dim3(64, 4, 3), 256, 0, stream>>>(Xb, Wqt, bq, bk, bv, Qb);

    if (ws_size >= FULL_NEED) {
        attn_pass1p<<<dim3(32, 16, 2), 256, 0, stream>>>(Qb, Kb, statsP, Pbuf);
        colsum_fused<<<dim3(16, 16, 2), 256, 0, stream>>>(Pbuf, statsP, Sg);
    } else {
        legacy_pass1<<<dim3(32, 16, 2), 256, 0, stream>>>(Qb, Kb, statsP);
        legacy_reduce<<<32, 256, 0, stream>>>(statsP, cstat, Sg);
        legacy_pass2<<<dim3(32, 16, 2), 256, 0, stream>>>(Qb, Kb, cstat, Sg);
    }
    gemm_final<<<dim3(128, 4), 256, 0, stream>>>(Vb, Wot, Sg, bo, g, bb, mean, var,
                                                 X, out);
}

// Round 11
// 215.715 us; speedup vs baseline: 1.7315x; 1.0777x over previous
//
#include <hip/hip_runtime.h>
#include <hip/hip_bf16.h>

typedef unsigned short u16;
typedef unsigned int u32;
typedef __attribute__((ext_vector_type(8))) short short8;
typedef __attribute__((ext_vector_type(4))) float f32x4;

__device__ __forceinline__ u16 f2bf(float f) {
    union { float f; unsigned u; } v; v.f = f;
    unsigned r = v.u + 0x7fffu + ((v.u >> 16) & 1u);
    return (u16)(r >> 16);
}

__device__ __forceinline__ float fexp2(float x) {
#if __has_builtin(__builtin_amdgcn_exp2f)
    return __builtin_amdgcn_exp2f(x);
#else
    return __expf(x * 0.6931471805599453f);
#endif
}

// ---------------------------------------------------------------------------
// fp8 e4m3 pack/unpack (P pre-scaled x256 so [2^-17,1] is normal range;
// ~6% rel err -> scale err <=1.5% at the EPS knee; r9/r10 absmax 0.078).
// ---------------------------------------------------------------------------
#if __has_builtin(__builtin_amdgcn_cvt_pk_fp8_f32) && \
    __has_builtin(__builtin_amdgcn_cvt_f32_fp8)
#define FP8_HW 1
#else
#define FP8_HW 0
#endif

#if !FP8_HW
__device__ __forceinline__ u32 sw_fp8(float x) {  // x in [0, 448]
    union { float f; u32 u; } v; v.f = x;
    int E = (int)(v.u >> 23) - 127;
    if (x < 0.001953125f) return 0;                       // < 2^-9
    if (E < -6) return (u32)(x * 512.0f + 0.5f);          // subnormal
    u32 m = v.u & 0x7fffffu;
    u32 r = (m + 0x80000u) >> 20;
    u32 bits = ((u32)(E + 7) << 3) + r;
    return bits > 0x7eu ? 0x7eu : bits;
}
__device__ __forceinline__ float sw_fp8d(u32 b) {
    u32 e = (b >> 3) & 15u, m = b & 7u;
    if (e == 0) return (float)m * 0.001953125f;
    union { u32 u; float f; } v; v.u = ((e + 120u) << 23) | (m << 20);
    return v.f;
}
#endif

__device__ __forceinline__ u32 fp8x4_pack(float p0, float p1, float p2, float p3) {
#if FP8_HW
    u32 v = (u32)__builtin_amdgcn_cvt_pk_fp8_f32(p0, p1, 0, false);
    v = (u32)__builtin_amdgcn_cvt_pk_fp8_f32(p2, p3, (int)v, true);
    return v;
#else
    return sw_fp8(p0) | (sw_fp8(p1) << 8) | (sw_fp8(p2) << 16) | (sw_fp8(p3) << 24);
#endif
}

#if FP8_HW
#define FP8_DEC(v, s) __builtin_amdgcn_cvt_f32_fp8((int)(v), (s))
#else
#define FP8_DEC(v, s) sw_fp8d(((v) >> ((s) * 8)) & 0xffu)
#endif

// async 16B global->LDS DMA (m97 pattern). lds base must be wave-uniform;
// each lane deposits at base + lane*16.
__device__ __forceinline__ void async_cp16(const u16* g, u16* l) {
    __builtin_amdgcn_global_load_lds(
        (const __attribute__((address_space(1))) void*)g,
        (__attribute__((address_space(3))) void*)l, 16, 0, 0);
}

// ---------------------------------------------------------------------------
// XOR-swizzled LDS GEMM cores (r6: zero SQ_LDS_BANK_CONFLICT).
// Store granule G of each 16-row window at position P = G ^ ((G>>3)&7).
// ---------------------------------------------------------------------------

// 128x128x512: A [128,512] bf16 rm, B^T [128,512] bf16 rm (computes A.B^T).
__device__ __forceinline__ void gemm512(const u16* __restrict__ A,
                                        const u16* __restrict__ B,
                                        u16* As, u16* Bs,
                                        f32x4 acc[4][4], int tid) {
    const int lane = tid & 63, w = tid >> 6;
    const int quad = lane >> 4, l15 = lane & 15;
    const int wm = tid >> 7, wn = (tid >> 6) & 1;
    const int Gw = lane ^ ((lane >> 3) & 7);
    const int srow = Gw >> 2;
    const int scol = (Gw & 3) * 8;
    const int arow0 = w * 32 + srow, arow1 = arow0 + 16;
    u16* la0 = As + (w * 2 + 0) * 512;
    u16* la1 = As + (w * 2 + 1) * 512;
    u16* lb0 = Bs + (w * 2 + 0) * 512;
    u16* lb1 = Bs + (w * 2 + 1) * 512;
    const int Pr8 = ((l15 * 4 + quad) ^ (l15 >> 1)) * 8;
    for (int k0 = 0; k0 < 512; k0 += 32) {
        __syncthreads();
        async_cp16(A + (size_t)arow0 * 512 + k0 + scol, la0);
        async_cp16(A + (size_t)arow1 * 512 + k0 + scol, la1);
        async_cp16(B + (size_t)arow0 * 512 + k0 + scol, lb0);
        async_cp16(B + (size_t)arow1 * 512 + k0 + scol, lb1);
        __syncthreads();
        short8 af[4], bfr[4];
#pragma unroll
        for (int i = 0; i < 4; i++)
            af[i] = *(const short8*)&As[(wm * 64 + i * 16) * 32 + Pr8];
#pragma unroll
        for (int j = 0; j < 4; j++)
            bfr[j] = *(const short8*)&Bs[(wn * 64 + j * 16) * 32 + Pr8];
#pragma unroll
        for (int i = 0; i < 4; i++)
#pragma unroll
            for (int j = 0; j < 4; j++)
                acc[i][j] = __builtin_amdgcn_mfma_f32_16x16x32_bf16(
                    af[i], bfr[j], acc[i][j], 0, 0, 0);
    }
}

// 64x128x512 variant (A 64 rows) for gemm_final.
__device__ __forceinline__ void gemm512_r64(const u16* __restrict__ A,
                                            const u16* __restrict__ B,
                                            u16* As, u16* Bs,
                                            f32x4 acc[2][4], int tid) {
    const int lane = tid & 63, w = tid >> 6;
    const int quad = lane >> 4, l15 = lane & 15;
    const int wm = tid >> 7, wn = (tid >> 6) & 1;
    const int Gw = lane ^ ((lane >> 3) & 7);
    const int srow = Gw >> 2;
    const int scol = (Gw & 3) * 8;
    const int arowA = w * 16 + srow;
    const int arowB0 = (w * 2 + 0) * 16 + srow;
    const int arowB1 = (w * 2 + 1) * 16 + srow;
    u16* la = As + w * 512;
    u16* lb0 = Bs + (w * 2 + 0) * 512;
    u16* lb1 = Bs + (w * 2 + 1) * 512;
    const int Pr8 = ((l15 * 4 + quad) ^ (l15 >> 1)) * 8;
    for (int k0 = 0; k0 < 512; k0 += 32) {
        __syncthreads();
        async_cp16(A + (size_t)arowA * 512 + k0 + scol, la);
        async_cp16(B + (size_t)arowB0 * 512 + k0 + scol, lb0);
        async_cp16(B + (size_t)arowB1 * 512 + k0 + scol, lb1);
        __syncthreads();
        short8 af[2], bfr[4];
#pragma unroll
        for (int i = 0; i < 2; i++)
            af[i] = *(const short8*)&As[(wm * 32 + i * 16) * 32 + Pr8];
#pragma unroll
        for (int j = 0; j < 4; j++)
            bfr[j] = *(const short8*)&Bs[(wn * 64 + j * 16) * 32 + Pr8];
#pragma unroll
        for (int i = 0; i < 2; i++)
#pragma unroll
            for (int j = 0; j < 4; j++)
                acc[i][j] = __builtin_amdgcn_mfma_f32_16x16x32_bf16(
                    af[i], bfr[j], acc[i][j], 0, 0, 0);
    }
}

// ---------------------------------------------------------------------------
// Fused prep: [0,4096) convert X->bf16; [4096,5120) transpose weights;
// 5120: zero Sg (per-launch, graph-safe).
// ---------------------------------------------------------------------------
__global__ void prep(const float* __restrict__ X, const float* __restrict__ W0,
                     const float* __restrict__ W1, const float* __restrict__ W2,
                     const float* __restrict__ W3, u16* __restrict__ Xb,
                     u16* __restrict__ T0, u16* __restrict__ T1,
                     u16* __restrict__ T2, u16* __restrict__ T3,
                     float* __restrict__ Sg) {
    __shared__ float tile[32][33];
    int id = blockIdx.x, tid = threadIdx.x;
    if (id == 5120) {
        float4 z = {0.f, 0.f, 0.f, 0.f};
#pragma unroll
        for (int t = 0; t < 8; t++) ((float4*)Sg)[tid + t * 256] = z;
        return;
    }
    if (id < 4096) {
        int idx = (id * 256 + tid) * 4;
        float4 v = *(const float4*)&X[idx];
        ushort4 o;
        o.x = f2bf(v.x); o.y = f2bf(v.y); o.z = f2bf(v.z); o.w = f2bf(v.w);
        *(ushort4*)&Xb[idx] = o;
        return;
    }
    int t = id - 4096;
    int z = t >> 8, rem = t & 255;
    int bo_ = (rem & 15) * 32, bi = (rem >> 4) * 32;
    const float* src; u16* dst;
    switch (z) {
        case 0: src = W0; dst = T0; break;
        case 1: src = W1; dst = T1; break;
        case 2: src = W2; dst = T2; break;
        default: src = W3; dst = T3; break;
    }
    int tx = tid & 31, ty = tid >> 5;
#pragma unroll
    for (int s = 0; s < 4; s++) {
        int i = bi + ty + s * 8;
        tile[ty + s * 8][tx] = src[i * 512 + bo_ + tx];
    }
    __syncthreads();
#pragma unroll
    for (int s = 0; s < 4; s++) {
        int o = bo_ + ty + s * 8;
        dst[o * 512 + bi + tx] = f2bf(tile[tx][ty + s * 8]);
    }
}

// ---------------------------------------------------------------------------
// Fused QKV projection. z==0 (Q) scaled by log2(e) -> base-2 score domain.
// ---------------------------------------------------------------------------
__global__ __launch_bounds__(256) void gemm_qkv(
    const u16* __restrict__ Xb, const u16* __restrict__ Wall,
    const float* __restrict__ bq, const float* __restrict__ bk,
    const float* __restrict__ bv, u16* __restrict__ Qall) {
    __shared__ __align__(16) u16 As[128 * 32];
    __shared__ __align__(16) u16 Bs[128 * 32];
    int tid = threadIdx.x;
    int m0 = blockIdx.x * 128, n0 = blockIdx.y * 128, z = blockIdx.z;
    const u16* Bt = Wall + (size_t)z * 262144 + (size_t)n0 * 512;
    const float* bias = (z == 0) ? bq : (z == 1) ? bk : bv;
    const float qs = (z == 0) ? 1.44269504088896340736f : 1.0f;
    u16* C = Qall + (size_t)z * 4194304;
    f32x4 acc[4][4];
#pragma unroll
    for (int i = 0; i < 4; i++)
#pragma unroll
        for (int j = 0; j < 4; j++) acc[i][j] = (f32x4){0.f, 0.f, 0.f, 0.f};
    gemm512(Xb + (size_t)m0 * 512, Bt, As, Bs, acc, tid);
    int lane = tid & 63, quad = lane >> 4, l15 = lane & 15;
    int wm = tid >> 7, wn = (tid >> 6) & 1;
#pragma unroll
    for (int j = 0; j < 4; j++) {
        int n = n0 + wn * 64 + j * 16 + l15;
        float bvv = bias[n];
#pragma unroll
        for (int i = 0; i < 4; i++)
#pragma unroll
            for (int rg = 0; rg < 4; rg++) {
                int m = m0 + wm * 64 + i * 16 + quad * 4 + rg;
                C[(size_t)m * 512 + n] = f2bf((acc[i][j][rg] + bvv) * qs);
            }
    }
}

// ---------------------------------------------------------------------------
// Pass 1, fp8 P-store: per 128x128 score tile, per-64-col-chunk row-max Mt;
// P = exp2(s - Mt + 8) packed fp8x4, value-major [g][tid] (coalesced);
// stats (Mt, L). grid (32, 16, 2). (unchanged from r10: 74 us measured)
// ---------------------------------------------------------------------------
__global__ __launch_bounds__(256) void attn_pass1p(
    const u16* __restrict__ Qb, const u16* __restrict__ Kb,
    float2* __restrict__ statsP, u32* __restrict__ Pbuf) {
    __shared__ __align__(16) u16 As[128 * 32];
    __shared__ __align__(16) u16 Bs[128 * 32];
    int tid = threadIdx.x;
    int mblk = blockIdx.x, nch = blockIdx.y, b = blockIdx.z;
    const u16* Q = Qb + ((size_t)(b * 4096 + mblk * 128)) * 512;
    int lane = tid & 63, quad = lane >> 4, l15 = lane & 15;
    int wm = tid >> 7, wn = (tid >> 6) & 1;
    for (int nt = 0; nt < 2; nt++) {
        const u16* K = Kb + ((size_t)(b * 4096 + nch * 256 + nt * 128)) * 512;
        f32x4 acc[4][4];
#pragma unroll
        for (int i = 0; i < 4; i++)
#pragma unroll
            for (int j = 0; j < 4; j++) acc[i][j] = (f32x4){0.f, 0.f, 0.f, 0.f};
        gemm512(Q, K, As, Bs, acc, tid);
        u32* Pt = Pbuf + (((size_t)(b * 32 + mblk) * 16 + nch) * 2 + nt) * 4096;
        int ch = nch * 4 + nt * 2 + wn;
#pragma unroll
        for (int i = 0; i < 4; i++)
#pragma unroll
            for (int rg = 0; rg < 4; rg++) {
                float v0 = acc[i][0][rg], v1 = acc[i][1][rg];
                float v2 = acc[i][2][rg], v3 = acc[i][3][rg];
                float Mt = fmaxf(fmaxf(v0, v1), fmaxf(v2, v3));
                Mt = fmaxf(Mt, __shfl_xor(Mt, 1));
                Mt = fmaxf(Mt, __shfl_xor(Mt, 2));
                Mt = fmaxf(Mt, __shfl_xor(Mt, 4));
                Mt = fmaxf(Mt, __shfl_xor(Mt, 8));  // uniform over 16 l15 lanes
                float e8 = Mt - 8.0f;  // x256 pre-scale for fp8 range
                float p0 = fexp2(v0 - e8), p1 = fexp2(v1 - e8);
                float p2 = fexp2(v2 - e8), p3 = fexp2(v3 - e8);
                Pt[(i * 4 + rg) * 256 + tid] = fp8x4_pack(p0, p1, p2, p3);
                float L = p0 + p1 + p2 + p3;
                L += __shfl_xor(L, 1);
                L += __shfl_xor(L, 2);
                L += __shfl_xor(L, 4);
                L += __shfl_xor(L, 8);
                if (l15 == 0)
                    statsP[((size_t)(b * 64 + ch)) * 4096 + mblk * 128 +
                           wm * 64 + i * 16 + quad * 4 + rg] =
                        make_float2(Mt, L * 0.00390625f);  // true L_ch
            }
    }
}

// ---------------------------------------------------------------------------
// c = M + log2(Z) per row. Separate kernel (r10 fused it into colsum with
// 64x redundancy -> +10us regression; r7 retained-array version spilled).
// Register-light streaming; grid 32 x 256.
// ---------------------------------------------------------------------------
__global__ void reduce_stats2(const float2* __restrict__ statsP,
                              float* __restrict__ cstat) {
    int t = blockIdx.x * 256 + threadIdx.x;
    int b = t >> 12, m = t & 4095;
    const float2* sp = statsP + (size_t)b * 64 * 4096 + m;
    float M = -INFINITY;
#pragma unroll 4
    for (int ch = 0; ch < 64; ch++) M = fmaxf(M, sp[(size_t)ch * 4096].x);
    float Z = 0.f;
#pragma unroll 4
    for (int ch = 0; ch < 64; ch++) {
        float2 p = sp[(size_t)ch * 4096];
        Z += p.y * fexp2(p.x - M);
    }
    cstat[t] = M + __log2f(Z);
}

// ---------------------------------------------------------------------------
// Weighted column sums: S[n] += sum_m P_fp8[m,n] * exp2(Mt[m]-8-c[m]).
// F-SKIP: if all 4 F factors < 2^-58, the 16 P loads+decodes are skipped —
// dropped mass per column <= 4096*256*2^-58 = 2^-38 (P<=256!), scale err
// <=3.6e-3. ~40-50% of (row-group, chunk) pairs skip (hard-softmax).
// grid (nch=16, y = nt + 2*mgrp (16 mgrps of 2 mblks), b=2) = 1024 blocks.
// ---------------------------------------------------------------------------
__global__ __launch_bounds__(256) void colsum(
    const u32* __restrict__ Pbuf, const float2* __restrict__ statsP,
    const float* __restrict__ cstat, float* __restrict__ Sg) {
    int tid = threadIdx.x, lane = tid & 63;
    int wm = tid >> 7, wn = (tid >> 6) & 1, quad = lane >> 4;
    int nch = blockIdx.x, nt = blockIdx.y & 1, mgrp = blockIdx.y >> 1;
    int b = blockIdx.z;
    int ch = nch * 4 + nt * 2 + wn;
    const float2* Sp = statsP + ((size_t)(b * 64 + ch)) * 4096;
    const float* Cp = cstat + (size_t)b * 4096;
    float cp[4] = {0.f, 0.f, 0.f, 0.f};
    for (int mb = 0; mb < 2; mb++) {
        int mblk = mgrp * 2 + mb;
        const u32* Pt =
            Pbuf + (((size_t)(b * 32 + mblk) * 16 + nch) * 2 + nt) * 4096;
#pragma unroll
        for (int i = 0; i < 4; i++) {
            int r0 = mblk * 128 + wm * 64 + i * 16 + quad * 4;
            float4 s01 = *(const float4*)&Sp[r0];      // (M0,L0,M1,L1)
            float4 s23 = *(const float4*)&Sp[r0 + 2];  // (M2,L2,M3,L3)
            float4 cv = *(const float4*)&Cp[r0];
            float fv[4] = {fexp2(s01.x - 8.0f - cv.x),
                           fexp2(s01.z - 8.0f - cv.y),
                           fexp2(s23.x - 8.0f - cv.z),
                           fexp2(s23.z - 8.0f - cv.w)};
            float fm = fmaxf(fmaxf(fv[0], fv[1]), fmaxf(fv[2], fv[3]));
            if (fm > 3.469446951953614e-18f) {  // 2^-58: see header comment
#pragma unroll
                for (int rg = 0; rg < 4; rg++) {
                    u32 e = Pt[(i * 4 + rg) * 256 + tid];
                    cp[0] += FP8_DEC(e, 0) * fv[rg];
                    cp[1] += FP8_DEC(e, 1) * fv[rg];
                    cp[2] += FP8_DEC(e, 2) * fv[rg];
                    cp[3] += FP8_DEC(e, 3) * fv[rg];
                }
            }
        }
    }
#pragma unroll
    for (int j = 0; j < 4; j++) {
        float s = cp[j];
        s += __shfl_xor(s, 16);
        s += __shfl_xor(s, 32);
        if (lane < 16)
            atomicAdd(&Sg[b * 4096 + nch * 256 + nt * 128 + wn * 64 + j * 16 + lane], s);
    }
}

// ---------------------------------------------------------------------------
// LEGACY fallback (round-6 flow) if ws_size can't hold Pbuf.
// ---------------------------------------------------------------------------
__global__ __launch_bounds__(256) void legacy_pass1(
    const u16* __restrict__ Qb, const u16* __restrict__ Kb,
    float2* __restrict__ statsP) {
    __shared__ __align__(16) u16 As[128 * 32];
    __shared__ __align__(16) u16 Bs[128 * 32];
    int tid = threadIdx.x;
    int mblk = blockIdx.x, nch = blockIdx.y, b = blockIdx.z;
    const u16* Q = Qb + ((size_t)(b * 4096 + mblk * 128)) * 512;
    int lane = tid & 63, quad = lane >> 4, l15 = lane & 15;
    int wm = tid >> 7, wn = (tid >> 6) & 1;
    float runM[4][4], runL[4][4];
#pragma unroll
    for (int i = 0; i < 4; i++)
#pragma unroll
        for (int rg = 0; rg < 4; rg++) { runM[i][rg] = -INFINITY; runL[i][rg] = 0.f; }
    for (int nt = 0; nt < 2; nt++) {
        const u16* K = Kb + ((size_t)(b * 4096 + nch * 256 + nt * 128)) * 512;
        f32x4 acc[4][4];
#pragma unroll
        for (int i = 0; i < 4; i++)
#pragma unroll
            for (int j = 0; j < 4; j++) acc[i][j] = (f32x4){0.f, 0.f, 0.f, 0.f};
        gemm512(Q, K, As, Bs, acc, tid);
#pragma unroll
        for (int i = 0; i < 4; i++)
#pragma unroll
            for (int rg = 0; rg < 4; rg++) {
                float v0 = acc[i][0][rg], v1 = acc[i][1][rg];
                float v2 = acc[i][2][rg], v3 = acc[i][3][rg];
                float vm = fmaxf(fmaxf(v0, v1), fmaxf(v2, v3));
                float mo = runM[i][rg];
                if (vm > mo - 30.f) {
                    float nm = fmaxf(mo, vm);
                    runL[i][rg] = runL[i][rg] * fexp2(mo - nm) +
                                  fexp2(v0 - nm) + fexp2(v1 - nm) +
                                  fexp2(v2 - nm) + fexp2(v3 - nm);
                    runM[i][rg] = nm;
                }
            }
    }
#pragma unroll
    for (int i = 0; i < 4; i++)
#pragma unroll
        for (int rg = 0; rg < 4; rg++) {
            float M = runM[i][rg];
            float Mf = M;
#pragma unroll
            for (int d = 1; d < 16; d <<= 1) Mf = fmaxf(Mf, __shfl_xor(Mf, d));
            float L = runL[i][rg] * fexp2(M - Mf);
#pragma unroll
            for (int d = 1; d < 16; d <<= 1) L += __shfl_xor(L, d);
            if (l15 == 0)
                statsP[((size_t)(b * 32 + nch * 2 + wn)) * 4096 +
                       mblk * 128 + wm * 64 + i * 16 + quad * 4 + rg] =
                    make_float2(Mf, L);
        }
}

__global__ void legacy_reduce(const float2* __restrict__ statsP,
                              float* __restrict__ cstat, float* __restrict__ Sg) {
    int t = blockIdx.x * 256 + threadIdx.x;
    int b = t >> 12, m = t & 4095;
    const float2* sp = statsP + (size_t)b * 32 * 4096 + m;
    float M = -INFINITY;
#pragma unroll 4
    for (int ch = 0; ch < 32; ch++) M = fmaxf(M, sp[(size_t)ch * 4096].x);
    float L = 0.f;
#pragma unroll 4
    for (int ch = 0; ch < 32; ch++) {
        float2 p = sp[(size_t)ch * 4096];
        L += p.y * fexp2(p.x - M);
    }
    cstat[t] = M + __log2f(L);
    Sg[t] = 0.f;
}

__global__ __launch_bounds__(256) void legacy_pass2(
    const u16* __restrict__ Qb, const u16* __restrict__ Kb,
    const float* __restrict__ cstat, float* __restrict__ Sg) {
    __shared__ __align__(16) u16 As[128 * 32];
    __shared__ __align__(16) u16 Bs[128 * 32];
    int tid = threadIdx.x;
    int nblk = blockIdx.x, mch = blockIdx.y, b = blockIdx.z;
    const u16* K = Kb + ((size_t)(b * 4096 + nblk * 128)) * 512;
    int lane = tid & 63, quad = lane >> 4;
    int wm = tid >> 7, wn = (tid >> 6) & 1;
    float cp0 = 0.f, cp1 = 0.f, cp2 = 0.f, cp3 = 0.f;
    for (int mt = 0; mt < 2; mt++) {
        int m0 = mch * 256 + mt * 128;
        const u16* Q = Qb + ((size_t)(b * 4096 + m0)) * 512;
        f32x4 acc[4][4];
#pragma unroll
        for (int i = 0; i < 4; i++)
#pragma unroll
            for (int j = 0; j < 4; j++) acc[i][j] = (f32x4){0.f, 0.f, 0.f, 0.f};
        gemm512(Q, K, As, Bs, acc, tid);
        float4 c4[4];
#pragma unroll
        for (int i = 0; i < 4; i++)
            c4[i] = *(const float4*)&cstat[b * 4096 + m0 + wm * 64 + i * 16 + quad * 4];
#pragma unroll
        for (int i = 0; i < 4; i++) {
            float cc[4] = {c4[i].x, c4[i].y, c4[i].z, c4[i].w};
#pragma unroll
            for (int rg = 0; rg < 4; rg++) {
                float c = cc[rg];
                float v0 = acc[i][0][rg] - c, v1 = acc[i][1][rg] - c;
                float v2 = acc[i][2][rg] - c, v3 = acc[i][3][rg] - c;
                float vm = fmaxf(fmaxf(v0, v1), fmaxf(v2, v3));
                if (vm > -60.f) {
                    cp0 += fexp2(v0); cp1 += fexp2(v1);
                    cp2 += fexp2(v2); cp3 += fexp2(v3);
                }
            }
        }
    }
    float cps[4] = {cp0, cp1, cp2, cp3};
#pragma unroll
    for (int j = 0; j < 4; j++) {
        float s = cps[j];
        s += __shfl_xor(s, 16);
        s += __shfl_xor(s, 32);
        if (lane < 16)
            atomicAdd(&Sg[b * 4096 + nblk * 128 + wn * 64 + j * 16 + lane], s);
    }
}

// ---------------------------------------------------------------------------
// Final: out = relu(BN((V*rowscale) . Wo^T + bo)) + X  (fp32 out)
// 64x128 tiles, grid (128, 4). m0 in [0,8192) == flat (b,m).
// ---------------------------------------------------------------------------
__global__ __launch_bounds__(256) void gemm_final(
    const u16* __restrict__ A, const u16* __restrict__ Bt,
    const float* __restrict__ Sg, const float* __restrict__ bo,
    const float* __restrict__ g, const float* __restrict__ bb,
    const float* __restrict__ mean, const float* __restrict__ var,
    const float* __restrict__ X, float* __restrict__ out) {
    __shared__ __align__(16) u16 As[64 * 32];
    __shared__ __align__(16) u16 Bs[128 * 32];
    int tid = threadIdx.x;
    int m0 = blockIdx.x * 64, n0 = blockIdx.y * 128;
    f32x4 acc[2][4];
#pragma unroll
    for (int i = 0; i < 2; i++)
#pragma unroll
        for (int j = 0; j < 4; j++) acc[i][j] = (f32x4){0.f, 0.f, 0.f, 0.f};
    gemm512_r64(A + (size_t)m0 * 512, Bt + (size_t)n0 * 512, As, Bs, acc, tid);
    int lane = tid & 63, quad = lane >> 4, l15 = lane & 15;
    int wm = tid >> 7, wn = (tid >> 6) & 1;
    float sc[2][4];
#pragma unroll
    for (int i = 0; i < 2; i++) {
        float4 s = *(const float4*)&Sg[m0 + wm * 32 + i * 16 + quad * 4];
        float v[4] = {s.x, s.y, s.z, s.w};
#pragma unroll
        for (int rg = 0; rg < 4; rg++) sc[i][rg] = v[rg] / (1e-9f + v[rg]);
    }
#pragma unroll
    for (int j = 0; j < 4; j++) {
        int n = n0 + wn * 64 + j * 16 + l15;
        float aj = rsqrtf(var[n] + 1e-5f) * g[n];
        float cj = bb[n] - mean[n] * aj;
        float bj = bo[n];
#pragma unroll
        for (int i = 0; i < 2; i++)
#pragma unroll
            for (int rg = 0; rg < 4; rg++) {
                int m = m0 + wm * 32 + i * 16 + quad * 4 + rg;
                float x = acc[i][j][rg] * sc[i][rg] + bj;
                float y = x * aj + cj;
                out[(size_t)m * 512 + n] = fmaxf(y, 0.f) + X[(size_t)m * 512 + n];
            }
    }
}

// ---------------------------------------------------------------------------
extern "C" void kernel_launch(void* const* d_in, const int* in_sizes, int n_in,
                              void* d_out, int out_size, void* d_ws, size_t ws_size,
                              hipStream_t stream) {
    const float* X  = (const float*)d_in[0];
    const float* Wq = (const float*)d_in[1];
    const float* Wk = (const float*)d_in[2];
    const float* Wv = (const float*)d_in[3];
    const float* Wo = (const float*)d_in[4];
    const float* bq = (const float*)d_in[5];
    const float* bk = (const float*)d_in[6];
    const float* bv = (const float*)d_in[7];
    const float* bo = (const float*)d_in[8];
    const float* g    = (const float*)d_in[9];
    const float* bb   = (const float*)d_in[10];
    const float* mean = (const float*)d_in[11];
    const float* var  = (const float*)d_in[12];
    float* out = (float*)d_out;

    char* ws = (char*)d_ws;
    u16* Xb  = (u16*)(ws + 0);                    // 8 MB
    u16* Wqt = (u16*)(ws + 8388608);              // 4x512KB (Wq,Wk,Wv,Wo)
    u16* Wot = (u16*)(ws + 9961472);
    u16* Qb  = (u16*)(ws + 10485760);             // Q,K,V contiguous 3x8MB
    u16* Kb  = (u16*)(ws + 18874368);
    u16* Vb  = (u16*)(ws + 27262976);
    float2* statsP = (float2*)(ws + 35651584);    // [b][64][4096] f2 = 4 MB
    float* Sg      = (float*)(ws + 39845888);     // 32 KB
    float* cstat   = (float*)(ws + 39878656);     // 32 KB
    u32* Pbuf      = (u32*)(ws + 39911424);       // 32 MB fp8 P

    const size_t FULL_NEED = 39911424ull + 33554432ull;  // ~70 MB

    prep<<<5121, 256, 0, stream>>>(X, Wq, Wk, Wv, Wo, Xb, Wqt, Wqt + 262144,
                                   Wqt + 524288, Wot, Sg);
    gemm_qkv<<<dim3(64, 4, 3), 256, 0, stream>>>(Xb, Wqt, bq, bk, bv, Qb);

    if (ws_size >= FULL_NEED) {
        attn_pass1p<<<dim3(32, 16, 2), 256, 0, stream>>>(Qb, Kb, statsP, Pbuf);
        reduce_stats2<<<32, 256, 0, stream>>>(statsP, cstat);
        colsum<<<dim3(16, 32, 2), 256, 0, stream>>>(Pbuf, statsP, cstat, Sg);
    } else {
        legacy_pass1<<<dim3(32, 16, 2), 256, 0, stream>>>(Qb, Kb, statsP);
        legacy_reduce<<<32, 256, 0, stream>>>(statsP, cstat, Sg);
        legacy_pass2<<<dim3(32, 16, 2), 256, 0, stream>>>(Qb, Kb, cstat, Sg);
    }
    gemm_final<<<dim3(128, 4), 256, 0, stream>>>(Vb, Wot, Sg, bo, g, bb, mean, var,
                                                 X, out);
}